// Round 1
// baseline (543.578 us; speedup 1.0000x reference)
//
#include <hip/hip_runtime.h>
#include <hip/hip_bf16.h>

#define S_DIM 4096
#define B_DIM 16
#define E_DIM 1024
#define D_DIM 1024
#define A_DIM 512
#define M_DIM (S_DIM * B_DIM)   // 65536 rows, row r = s*B + b

typedef __bf16 bf16x8 __attribute__((ext_vector_type(8)));
typedef float f32x4 __attribute__((ext_vector_type(4)));
typedef unsigned short u16;

__device__ __forceinline__ u16 f2bf(float f) {
    unsigned u = __builtin_bit_cast(unsigned, f);
    u += 0x7fffu + ((u >> 16) & 1u);   // RNE
    return (u16)(u >> 16);
}

// We [E][A] f32  ->  WeT [A][E] bf16 (so MFMA B-fragments are k-contiguous)
__global__ void k_transpose_we(const float* __restrict__ We, u16* __restrict__ WeT) {
    __shared__ float tile[32][33];
    const int e0 = blockIdx.x * 32;
    const int a0 = blockIdx.y * 32;
    const int tx = threadIdx.x, ty = threadIdx.y;   // 32 x 8
#pragma unroll
    for (int i = 0; i < 32; i += 8)
        tile[ty + i][tx] = We[(size_t)(e0 + ty + i) * A_DIM + a0 + tx];
    __syncthreads();
#pragma unroll
    for (int i = 0; i < 32; i += 8)
        WeT[(size_t)(a0 + ty + i) * E_DIM + e0 + tx] = f2bf(tile[tx][ty + i]);
}

// comb[b][a] = dec[b,:] . Wd[:,a] + bd[a] + be[a]
__global__ void k_comb(const float* __restrict__ dec, const float* __restrict__ Wd,
                       const float* __restrict__ bd, const float* __restrict__ be,
                       float* __restrict__ comb) {
    const int a = blockIdx.x * 256 + threadIdx.x;   // gridDim.x = 2
    const int b = blockIdx.y;
    float acc = bd[a] + be[a];
    const float* dptr = dec + (size_t)b * D_DIM;
    for (int d = 0; d < D_DIM; ++d)
        acc += dptr[d] * Wd[(size_t)d * A_DIM + a];
    comb[b * A_DIM + a] = acc;
}

// scores[r] = sum_a tanh(enc[r,:]@We[:,a] + comb[b,a]) * Ws[a] + bs
// Block: 64 rows x 512 cols, K=1024, BK=32, 512 threads = 8 waves (2x4).
__global__ __launch_bounds__(512, 4)
void k_scores(const float* __restrict__ enc, const u16* __restrict__ WeT,
              const float* __restrict__ comb, const float* __restrict__ Wsv,
              const float* __restrict__ bs, float* __restrict__ scores) {
    __shared__ u16 As[64 * 40];    // stride 40 shorts (pad 8) -> <=2-way bank alias
    __shared__ u16 Bs[512 * 40];
    __shared__ float sred[64];

    const int tid  = threadIdx.x;
    const int lane = tid & 63;
    const int wave = tid >> 6;
    const int wr = wave >> 2;            // 0..1  (rows)
    const int wc = wave & 3;             // 0..3  (cols)
    const int l15 = lane & 15, lhi = lane >> 4;
    const int blockRow = blockIdx.x * 64;

    if (tid < 64) sred[tid] = 0.f;

    f32x4 acc[2][8];
#pragma unroll
    for (int mf = 0; mf < 2; ++mf)
#pragma unroll
        for (int nf = 0; nf < 8; ++nf)
            acc[mf][nf] = f32x4{0.f, 0.f, 0.f, 0.f};

    const int arow = tid >> 3, ach = tid & 7;   // A stage: 64 rows x 8 float4
    const int brow = tid >> 2, bch = tid & 3;   // B stage: 128 rows x 4 uint4 per pass

    for (int k0 = 0; k0 < E_DIM; k0 += 32) {
        // stage A tile: 64x32 f32 -> bf16 in LDS
        {
            const float4 v = *reinterpret_cast<const float4*>(
                enc + (size_t)(blockRow + arow) * E_DIM + k0 + ach * 4);
            ushort4 h;
            h.x = f2bf(v.x); h.y = f2bf(v.y); h.z = f2bf(v.z); h.w = f2bf(v.w);
            *reinterpret_cast<ushort4*>(&As[arow * 40 + ach * 4]) = h;
        }
        // stage B tile: 512x32 bf16 from WeT (rows = a, contiguous in k)
#pragma unroll
        for (int p = 0; p < 4; ++p) {
            const int a = brow + p * 128;
            const uint4 w = *reinterpret_cast<const uint4*>(
                WeT + (size_t)a * E_DIM + k0 + bch * 8);
            *reinterpret_cast<uint4*>(&Bs[a * 40 + bch * 8]) = w;
        }
        __syncthreads();

        bf16x8 af[2];
#pragma unroll
        for (int mf = 0; mf < 2; ++mf)
            af[mf] = *reinterpret_cast<const bf16x8*>(
                &As[(wr * 32 + mf * 16 + l15) * 40 + lhi * 8]);
#pragma unroll
        for (int nf = 0; nf < 8; ++nf) {
            const bf16x8 bfv = *reinterpret_cast<const bf16x8*>(
                &Bs[(wc * 128 + nf * 16 + l15) * 40 + lhi * 8]);
            acc[0][nf] = __builtin_amdgcn_mfma_f32_16x16x32_bf16(af[0], bfv, acc[0][nf], 0, 0, 0);
            acc[1][nf] = __builtin_amdgcn_mfma_f32_16x16x32_bf16(af[1], bfv, acc[1][nf], 0, 0, 0);
        }
        __syncthreads();
    }

    // epilogue: x = acc + comb[b][C]; partial[row] += tanh(x)*Ws[C]
    float part[2][4] = {{0, 0, 0, 0}, {0, 0, 0, 0}};
#pragma unroll
    for (int nf = 0; nf < 8; ++nf) {
        const int C = wc * 128 + nf * 16 + l15;
        const float wsv = Wsv[C];
#pragma unroll
        for (int mf = 0; mf < 2; ++mf) {
#pragma unroll
            for (int j = 0; j < 4; ++j) {
                const int Rl = wr * 32 + mf * 16 + lhi * 4 + j;
                const int b = (blockRow + Rl) & (B_DIM - 1);
                const float x = acc[mf][nf][j] + comb[b * A_DIM + C];
                const float e = __expf(-2.f * fabsf(x));
                float th = (1.f - e) / (1.f + e);
                th = (x < 0.f) ? -th : th;
                part[mf][j] += th * wsv;
            }
        }
    }
    // reduce across the 16-lane column group (lanes differing in bits 0..3)
#pragma unroll
    for (int off = 1; off < 16; off <<= 1)
#pragma unroll
        for (int mf = 0; mf < 2; ++mf)
#pragma unroll
            for (int j = 0; j < 4; ++j)
                part[mf][j] += __shfl_xor(part[mf][j], off, 64);
    if (l15 == 0) {
#pragma unroll
        for (int mf = 0; mf < 2; ++mf)
#pragma unroll
            for (int j = 0; j < 4; ++j)
                atomicAdd(&sred[wr * 32 + mf * 16 + lhi * 4 + j], part[mf][j]);
    }
    __syncthreads();
    if (tid < 64) {
        const int r = blockRow + tid;
        // scores laid out [B][S] for coalesced softmax
        scores[(size_t)(r & (B_DIM - 1)) * S_DIM + (r >> 4)] = sred[tid] + bs[0];
    }
}

// softmax over S per b: alpha[b][s]
__global__ void k_softmax(const float* __restrict__ scores, float* __restrict__ alpha) {
    __shared__ float red[8];
    const int b = blockIdx.x;
    const int tid = threadIdx.x;   // 256
    const float* sc = scores + (size_t)b * S_DIM;
    float m = -1e30f;
    for (int i = tid; i < S_DIM; i += 256) m = fmaxf(m, sc[i]);
#pragma unroll
    for (int off = 32; off; off >>= 1) m = fmaxf(m, __shfl_xor(m, off, 64));
    if ((tid & 63) == 0) red[tid >> 6] = m;
    __syncthreads();
    m = fmaxf(fmaxf(red[0], red[1]), fmaxf(red[2], red[3]));
    float s = 0.f;
    for (int i = tid; i < S_DIM; i += 256) s += __expf(sc[i] - m);
#pragma unroll
    for (int off = 32; off; off >>= 1) s += __shfl_xor(s, off, 64);
    if ((tid & 63) == 0) red[4 + (tid >> 6)] = s;
    __syncthreads();
    const float inv = 1.f / (red[4] + red[5] + red[6] + red[7]);
    float* al = alpha + (size_t)b * S_DIM;
    for (int i = tid; i < S_DIM; i += 256) al[i] = __expf(sc[i] - m) * inv;
}

// contexts[b][e] = sum_s alpha[b][s] * enc[s][b][e]
__global__ void k_context(const float* __restrict__ enc, const float* __restrict__ alpha,
                          float* __restrict__ out) {
    const int b = blockIdx.y;        // 16
    const int chunk = blockIdx.x;    // 64 chunks of 64 timesteps
    const int tid = threadIdx.x;     // 256 -> float4 covers E=1024
    const int s0 = chunk * 64;
    float4 accv = make_float4(0.f, 0.f, 0.f, 0.f);
    for (int s = 0; s < 64; ++s) {
        const float al = alpha[(size_t)b * S_DIM + s0 + s];
        const float4 v = *reinterpret_cast<const float4*>(
            enc + ((size_t)(s0 + s) * B_DIM + b) * E_DIM + tid * 4);
        accv.x += al * v.x; accv.y += al * v.y;
        accv.z += al * v.z; accv.w += al * v.w;
    }
    float* o = out + (size_t)b * E_DIM + tid * 4;
    atomicAdd(o + 0, accv.x);
    atomicAdd(o + 1, accv.y);
    atomicAdd(o + 2, accv.z);
    atomicAdd(o + 3, accv.w);
}

extern "C" void kernel_launch(void* const* d_in, const int* in_sizes, int n_in,
                              void* d_out, int out_size, void* d_ws, size_t ws_size,
                              hipStream_t stream) {
    const float* enc = (const float*)d_in[0];
    const float* dec = (const float*)d_in[1];
    const float* We  = (const float*)d_in[2];
    const float* be  = (const float*)d_in[3];
    const float* Wd  = (const float*)d_in[4];
    const float* bd  = (const float*)d_in[5];
    const float* Ws  = (const float*)d_in[6];
    const float* bs  = (const float*)d_in[7];
    float* out = (float*)d_out;

    char* ws = (char*)d_ws;
    u16*   WeT    = (u16*)ws;                                   // 1 MB
    float* comb   = (float*)(ws + (1 << 20));                   // 32 KB
    float* scores = (float*)(ws + (1 << 20) + (32 << 10));      // 256 KB  [B][S]
    float* alpha  = (float*)(ws + (1 << 20) + (32 << 10) + (256 << 10)); // 256 KB

    hipLaunchKernelGGL(k_transpose_we, dim3(E_DIM / 32, A_DIM / 32), dim3(32, 8), 0, stream,
                       We, WeT);
    hipLaunchKernelGGL(k_comb, dim3(A_DIM / 256, B_DIM), dim3(256), 0, stream,
                       dec, Wd, bd, be, comb);
    hipLaunchKernelGGL(k_scores, dim3(M_DIM / 64), dim3(512), 0, stream,
                       enc, WeT, comb, Ws, bs, scores);
    hipLaunchKernelGGL(k_softmax, dim3(B_DIM), dim3(256), 0, stream, scores, alpha);
    hipMemsetAsync(d_out, 0, (size_t)B_DIM * E_DIM * sizeof(float), stream);
    hipLaunchKernelGGL(k_context, dim3(S_DIM / 64, B_DIM), dim3(256), 0, stream,
                       enc, alpha, out);
}

// Round 2
// 490.476 us; speedup vs baseline: 1.1083x; 1.1083x over previous
//
#include <hip/hip_runtime.h>
#include <hip/hip_bf16.h>

#define S_DIM 4096
#define B_DIM 16
#define E_DIM 1024
#define D_DIM 1024
#define A_DIM 512
#define M_DIM (S_DIM * B_DIM)
#define BK 64                 // k-step in elements (128 B bf16 rows -> clean XOR swizzle)
#define NKS (E_DIM / BK)      // 16
#define MT 64                 // rows per block

typedef __bf16 bf16x8 __attribute__((ext_vector_type(8)));
typedef float f32x4 __attribute__((ext_vector_type(4)));
typedef unsigned short u16;

__device__ __forceinline__ u16 f2bf(float f) {
    unsigned u = __builtin_bit_cast(unsigned, f);
    u += 0x7fffu + ((u >> 16) & 1u);   // RNE
    return (u16)(u >> 16);
}
__device__ __forceinline__ unsigned pack2(float a, float b) {
    return (unsigned)f2bf(a) | ((unsigned)f2bf(b) << 16);
}

// async global->LDS, 16 B per lane
__device__ __forceinline__ void gload_lds16(const void* g, void* l) {
    __builtin_amdgcn_global_load_lds(
        (const __attribute__((address_space(1))) unsigned*)g,
        (__attribute__((address_space(3))) unsigned*)l, 16, 0, 0);
}

// Build WeT_sw: [ks][a][64 shorts], 128 B rows with 16B-chunk XOR swizzle.
// Dest chunk d of row a holds true k-chunk c = d ^ (a&7).
__global__ void k_prep_we(const float* __restrict__ We, u16* __restrict__ WeT) {
    const int gid = blockIdx.x * 256 + threadIdx.x;   // 65536 total
    const int ks = gid >> 12, rem = gid & 4095;
    const int a = rem >> 3, d = rem & 7;
    const int c = d ^ (a & 7);
    const int e0 = ks * BK + c * 8;
    float v[8];
#pragma unroll
    for (int i = 0; i < 8; ++i) v[i] = We[(size_t)(e0 + i) * A_DIM + a];
    uint4 h;
    h.x = pack2(v[0], v[1]); h.y = pack2(v[2], v[3]);
    h.z = pack2(v[4], v[5]); h.w = pack2(v[6], v[7]);
    *reinterpret_cast<uint4*>(WeT + (size_t)ks * A_DIM * BK + a * BK + d * 8) = h;
}

// comb[b][a] = dec[b,:].Wd[:,a] + bd[a] + be[a]   grid(8,16) x 256
__global__ void k_comb(const float* __restrict__ dec, const float* __restrict__ Wd,
                       const float* __restrict__ bd, const float* __restrict__ be,
                       float* __restrict__ comb) {
    __shared__ float red[4][64];
    const int a0 = blockIdx.x * 64;
    const int b = blockIdx.y;
    const int t = threadIdx.x;
    const int al = t & 63, w = t >> 6;
    float acc = 0.f;
    const float* dp = dec + (size_t)b * D_DIM + w * 256;
    const float* wp = Wd + (size_t)w * 256 * A_DIM + a0 + al;
    for (int d = 0; d < 256; ++d)
        acc += dp[d] * wp[(size_t)d * A_DIM];
    red[w][al] = acc;
    __syncthreads();
    if (t < 64)
        comb[b * A_DIM + a0 + t] =
            red[0][t] + red[1][t] + red[2][t] + red[3][t] + bd[a0 + t] + be[a0 + t];
}

// scores[b][s] = sum_a tanh(enc@We + comb) * Ws   (bs dropped: softmax-invariant)
// 64 rows x 512 cols per block, BK=64, 4 waves (wave = 64x128), acc[4][8].
__global__ __launch_bounds__(256, 2)
void k_scores(const float* __restrict__ enc, const u16* __restrict__ WeT,
              const float* __restrict__ comb, const float* __restrict__ Wsv,
              float* __restrict__ scores) {
    __shared__ __align__(16) u16 As[MT * BK];       // 8 KB, 128 B rows, XOR-swizzled
    __shared__ __align__(16) u16 Bs[A_DIM * BK];    // 64 KB, same layout (linear copy of WeT_sw)

    const int tid = threadIdx.x;
    const int lane = tid & 63;
    const int wc = tid >> 6;                // wave id = column group
    const int l15 = lane & 15, lhi = lane >> 4;
    const int blockRow = blockIdx.x * MT;

    f32x4 acc[4][8];
#pragma unroll
    for (int mf = 0; mf < 4; ++mf)
#pragma unroll
        for (int nf = 0; nf < 8; ++nf)
            acc[mf][nf] = f32x4{0.f, 0.f, 0.f, 0.f};

    const int bOff = wc * 16384 + lane * 16;        // byte offset for B staging (per lane)

    for (int ks = 0; ks < NKS; ++ks) {
        const int k0 = ks * BK;
        // B stage: 64 KB linear async copy (pre-swizzled source)
        const char* gsrc = (const char*)WeT + (size_t)ks * A_DIM * BK * 2 + bOff;
        char* ldst = (char*)Bs + bOff;
#pragma unroll
        for (int i = 0; i < 16; ++i)
            gload_lds16(gsrc + i * 1024, ldst + i * 1024);
        // A stage: 64x64 f32->bf16, swizzled writes (chunk g: r=g>>3, d=g&7)
#pragma unroll
        for (int h = 0; h < 2; ++h) {
            const int g = tid + h * 256;
            const int r = g >> 3, d = g & 7;
            const int c = d ^ (r & 7);
            const float* src = enc + (size_t)(blockRow + r) * E_DIM + k0 + c * 8;
            const float4 v0 = *reinterpret_cast<const float4*>(src);
            const float4 v1 = *reinterpret_cast<const float4*>(src + 4);
            uint4 hh;
            hh.x = pack2(v0.x, v0.y); hh.y = pack2(v0.z, v0.w);
            hh.z = pack2(v1.x, v1.y); hh.w = pack2(v1.z, v1.w);
            *reinterpret_cast<uint4*>((char*)As + r * 128 + d * 16) = hh;
        }
        __syncthreads();
#pragma unroll
        for (int kk = 0; kk < 2; ++kk) {
            bf16x8 af[4];
#pragma unroll
            for (int mf = 0; mf < 4; ++mf) {
                const int rr = mf * 16 + l15;
                af[mf] = *reinterpret_cast<const bf16x8*>(
                    (const char*)As + rr * 128 + ((kk * 64 + lhi * 16) ^ ((rr & 7) << 4)));
            }
#pragma unroll
            for (int nf = 0; nf < 8; ++nf) {
                const int br = wc * 128 + nf * 16 + l15;
                const bf16x8 bfv = *reinterpret_cast<const bf16x8*>(
                    (const char*)Bs + br * 128 + ((kk * 64 + lhi * 16) ^ ((br & 7) << 4)));
#pragma unroll
                for (int mf = 0; mf < 4; ++mf)
                    acc[mf][nf] = __builtin_amdgcn_mfma_f32_16x16x32_bf16(
                        af[mf], bfv, acc[mf][nf], 0, 0, 0);
            }
        }
        __syncthreads();
    }

    // epilogue: comb -> LDS (reuse Bs), sred in As
    float* combLDS = reinterpret_cast<float*>(Bs);
    float* sred = reinterpret_cast<float*>(As);
#pragma unroll
    for (int i = 0; i < 8; ++i) {
        const int idx = tid + i * 256;   // 2048 float4 = 32 KB
        reinterpret_cast<float4*>(combLDS)[idx] = reinterpret_cast<const float4*>(comb)[idx];
    }
    if (tid < MT) sred[tid] = 0.f;
    __syncthreads();

    float part[4][4] = {};
#pragma unroll
    for (int nf = 0; nf < 8; ++nf) {
        const int C = wc * 128 + nf * 16 + l15;
        const float wsv = Wsv[C];
#pragma unroll
        for (int mf = 0; mf < 4; ++mf) {
#pragma unroll
            for (int j = 0; j < 4; ++j) {
                const int Rl = mf * 16 + lhi * 4 + j;
                const int b = (blockRow + Rl) & (B_DIM - 1);
                const float x = acc[mf][nf][j] + combLDS[b * A_DIM + C];
                const float e = __expf(-2.f * fabsf(x));
                float th = (1.f - e) / (1.f + e);
                th = (x < 0.f) ? -th : th;
                part[mf][j] += th * wsv;
            }
        }
    }
#pragma unroll
    for (int off = 1; off < 16; off <<= 1)
#pragma unroll
        for (int mf = 0; mf < 4; ++mf)
#pragma unroll
            for (int j = 0; j < 4; ++j)
                part[mf][j] += __shfl_xor(part[mf][j], off, 64);
    if (l15 == 0) {
#pragma unroll
        for (int mf = 0; mf < 4; ++mf)
#pragma unroll
            for (int j = 0; j < 4; ++j)
                atomicAdd(&sred[mf * 16 + lhi * 4 + j], part[mf][j]);
    }
    __syncthreads();
    if (tid < MT) {
        const int rr = blockRow + tid;
        scores[(size_t)(rr & (B_DIM - 1)) * S_DIM + (rr >> 4)] = sred[tid];
    }
}

__global__ void k_softmax(const float* __restrict__ scores, float* __restrict__ alpha) {
    __shared__ float red[8];
    const int b = blockIdx.x;
    const int tid = threadIdx.x;   // 256
    const float* sc = scores + (size_t)b * S_DIM;
    float m = -1e30f;
    for (int i = tid; i < S_DIM; i += 256) m = fmaxf(m, sc[i]);
#pragma unroll
    for (int off = 32; off; off >>= 1) m = fmaxf(m, __shfl_xor(m, off, 64));
    if ((tid & 63) == 0) red[tid >> 6] = m;
    __syncthreads();
    m = fmaxf(fmaxf(red[0], red[1]), fmaxf(red[2], red[3]));
    float s = 0.f;
    for (int i = tid; i < S_DIM; i += 256) s += __expf(sc[i] - m);
#pragma unroll
    for (int off = 32; off; off >>= 1) s += __shfl_xor(s, off, 64);
    if ((tid & 63) == 0) red[4 + (tid >> 6)] = s;
    __syncthreads();
    const float inv = 1.f / (red[4] + red[5] + red[6] + red[7]);
    float* al = alpha + (size_t)b * S_DIM;
    for (int i = tid; i < S_DIM; i += 256) al[i] = __expf(sc[i] - m) * inv;
}

// stage 1: per-(b, 64-s chunk) weighted partial sums (no atomics)
__global__ void k_ctx1(const float* __restrict__ enc, const float* __restrict__ alpha,
                       float* __restrict__ partial) {
    const int b = blockIdx.y, ch = blockIdx.x, tid = threadIdx.x;   // 256
    const int s0 = ch * 64;
    float4 av = make_float4(0.f, 0.f, 0.f, 0.f);
    const float* al = alpha + (size_t)b * S_DIM + s0;
    for (int s = 0; s < 64; ++s) {
        const float a = al[s];
        const float4 v = *reinterpret_cast<const float4*>(
            enc + ((size_t)(s0 + s) * B_DIM + b) * E_DIM + tid * 4);
        av.x += a * v.x; av.y += a * v.y; av.z += a * v.z; av.w += a * v.w;
    }
    reinterpret_cast<float4*>(partial)[((size_t)b * 64 + ch) * 256 + tid] = av;
}

// stage 2: reduce 64 chunks
__global__ void k_ctx2(const float* __restrict__ partial, float* __restrict__ out) {
    const int b = blockIdx.x, tid = threadIdx.x;   // 256
    float4 s = make_float4(0.f, 0.f, 0.f, 0.f);
    for (int c = 0; c < 64; ++c) {
        const float4 v = reinterpret_cast<const float4*>(partial)[((size_t)b * 64 + c) * 256 + tid];
        s.x += v.x; s.y += v.y; s.z += v.z; s.w += v.w;
    }
    reinterpret_cast<float4*>(out)[b * 256 + tid] = s;
}

extern "C" void kernel_launch(void* const* d_in, const int* in_sizes, int n_in,
                              void* d_out, int out_size, void* d_ws, size_t ws_size,
                              hipStream_t stream) {
    const float* enc = (const float*)d_in[0];
    const float* dec = (const float*)d_in[1];
    const float* We  = (const float*)d_in[2];
    const float* be  = (const float*)d_in[3];
    const float* Wd  = (const float*)d_in[4];
    const float* bd  = (const float*)d_in[5];
    const float* Ws  = (const float*)d_in[6];
    float* out = (float*)d_out;

    char* ws = (char*)d_ws;
    u16*   WeT     = (u16*)ws;                                  // 1 MB
    float* comb    = (float*)(ws + (1 << 20));                  // 32 KB
    float* scores  = (float*)(ws + (1 << 20) + (32 << 10));     // 256 KB [B][S]
    float* alpha   = (float*)(ws + (1 << 20) + (288 << 10));    // 256 KB
    float* partial = (float*)(ws + (1 << 20) + (544 << 10));    // 4 MB

    hipLaunchKernelGGL(k_prep_we, dim3(256), dim3(256), 0, stream, We, WeT);
    hipLaunchKernelGGL(k_comb, dim3(A_DIM / 64, B_DIM), dim3(256), 0, stream,
                       dec, Wd, bd, be, comb);
    hipLaunchKernelGGL(k_scores, dim3(M_DIM / MT), dim3(256), 0, stream,
                       enc, WeT, comb, Ws, scores);
    hipLaunchKernelGGL(k_softmax, dim3(B_DIM), dim3(256), 0, stream, scores, alpha);
    hipLaunchKernelGGL(k_ctx1, dim3(S_DIM / 64, B_DIM), dim3(256), 0, stream,
                       enc, alpha, partial);
    hipLaunchKernelGGL(k_ctx2, dim3(B_DIM), dim3(256), 0, stream, partial, out);
}